// Round 1
// baseline (318.497 us; speedup 1.0000x reference)
//
#include <hip/hip_runtime.h>
#include <stdint.h>

#define NT 2048     // tokens
#define TD 1024     // token dim
#define NH 16       // heads
#define KDZ 64      // head dim z
static constexpr float BETA = 0.125f;   // 1/sqrt(64)

typedef __attribute__((ext_vector_type(8))) short bf16x8;
typedef __attribute__((ext_vector_type(4))) float f32x4;
typedef __attribute__((address_space(3))) uint32_t lds_u32;
typedef __attribute__((address_space(1))) uint32_t glb_u32;

__device__ __forceinline__ float bf2f(unsigned short u){
  union { uint32_t u32; float f; } v; v.u32 = ((uint32_t)u) << 16; return v.f;
}
__device__ __forceinline__ unsigned short f2bf(float f){
  union { float f; uint32_t u; } v; v.f = f;
  uint32_t r = v.u + 0x7fffu + ((v.u >> 16) & 1u);   // RNE
  return (unsigned short)(r >> 16);
}

// ------------------------------------------------------------------
// prep: gbf = bf16(g); wkq = bf16([Wk;Wq]) rows hz2 x 1024;
//       twqk[d][j] = j<1024 ? Wq[j][d] : Wk[j-1024][d]  (bf16, 1024x2048)
// ------------------------------------------------------------------
__global__ __launch_bounds__(256) void prep_kernel(
    const float* __restrict__ g, const float* __restrict__ Wk, const float* __restrict__ Wq,
    unsigned short* __restrict__ gbf, unsigned short* __restrict__ wkq,
    unsigned short* __restrict__ twqk)
{
  int b = blockIdx.x;
  if (b < 1024) {
    int base = b * 2048 + threadIdx.x;
    #pragma unroll
    for (int i = 0; i < 8; i++) { int idx = base + i * 256; gbf[idx] = f2bf(g[idx]); }
  } else if (b < 2048) {
    int base = (b - 1024) * 2048 + threadIdx.x;
    #pragma unroll
    for (int i = 0; i < 8; i++) {
      int idx = base + i * 256;
      float v = (idx < (1 << 20)) ? Wk[idx] : Wq[idx - (1 << 20)];
      wkq[idx] = f2bf(v);
    }
  } else {
    int t = b - 2048;                  // 32 d-tiles x 64 j-tiles
    int dt = t & 31, jt = t >> 5;
    __shared__ float tile[32][33];
    int tx = threadIdx.x & 31, ty = threadIdx.x >> 5;
    int j0 = jt * 32, d0 = dt * 32;
    const float* src = (j0 < 1024) ? Wq : Wk;
    int jb = (j0 < 1024) ? j0 : (j0 - 1024);
    #pragma unroll
    for (int rr = 0; rr < 4; rr++)
      tile[ty + rr * 8][tx] = src[(size_t)(jb + ty + rr * 8) * 1024 + d0 + tx];
    __syncthreads();
    #pragma unroll
    for (int rr = 0; rr < 4; rr++)
      twqk[(size_t)(d0 + ty + rr * 8) * 2048 + j0 + tx] = f2bf(tile[tx][ty + rr * 8]);
  }
}

// ------------------------------------------------------------------
// transpose 2048x2048 bf16: out[j][m] = in[m][j]
// ------------------------------------------------------------------
__global__ __launch_bounds__(256) void transp_kernel(const unsigned short* __restrict__ in,
                                                     unsigned short* __restrict__ out)
{
  int t = blockIdx.x; int jt = t & 63, mt = t >> 6;
  __shared__ unsigned short tile[32][33];
  int tx = threadIdx.x & 31, ty = threadIdx.x >> 5;
  int m0 = mt * 32, j0 = jt * 32;
  #pragma unroll
  for (int rr = 0; rr < 4; rr++)
    tile[ty + rr * 8][tx] = in[(size_t)(m0 + ty + rr * 8) * 2048 + j0 + tx];
  __syncthreads();
  #pragma unroll
  for (int rr = 0; rr < 4; rr++)
    out[(size_t)(j0 + ty + rr * 8) * 2048 + m0 + tx] = tile[tx][ty + rr * 8];
}

// ------------------------------------------------------------------
// qst: QsT[r][q] = TKQ[1024+r][q] / L[r>>6][q]   (rows r = global z-index)
// ------------------------------------------------------------------
__global__ __launch_bounds__(256) void qst_kernel(const unsigned short* __restrict__ tkq,
                                                  const float* __restrict__ L,
                                                  unsigned short* __restrict__ qst, int rbase)
{
  int r = rbase + blockIdx.x;
  int h = r >> 6;
  const unsigned short* src = tkq + (size_t)(1024 + r) * 2048;
  unsigned short* dst = qst + (size_t)r * 2048;
  const float* Lh = L + (size_t)h * NT;
  for (int q = threadIdx.x; q < NT; q += 256)
    dst[q] = f2bf(bf2f(src[q]) / Lh[q]);
}

// ------------------------------------------------------------------
// bt-GEMM: C = A[M x K] * BT[N x K]^T, bf16 in, f32 acc (m97-style)
// 4 waves, wave-tile (TM/2 x TN/2), 16x16x32 bf16 MFMA, BK=32,
// global_load_lds(16B) staging into linear LDS.
// EPI 0: C0=bf16 C, ldc 2048                (K/Q gemm)
// EPI 1: P=exp(beta*acc) -> C0[z]=P, C1[z]=PT, atomicAdd L (scores)
// EPI 2: C0[r][hg*64+c]      = bf16(acc / L[hg][r])        (B1)
// EPI 3: C0[r][1024+hg*64+c] = bf16(acc)                   (B2)
// EPI 4: C0 f32 [r][c] = -acc                              (out)
// ------------------------------------------------------------------
template<int TM, int TN, int EPI>
__global__ __launch_bounds__(256) void btg_kernel(
    const unsigned short* __restrict__ A, int lda, long long sAz,
    const unsigned short* __restrict__ BT, int ldb, long long sBz,
    int Kdim, void* C0, void* C1, float* L, int hbase)
{
  constexpr int WM = TM / 2, WN = TN / 2, FM = WM / 16, FN = WN / 16;
  constexpr int AI = (TM * 64) / 4096, BI = (TN * 64) / 4096;
  __shared__ __align__(16) unsigned short As[TM * 32];
  __shared__ __align__(16) unsigned short Bs[TN * 32];
  int tid = threadIdx.x;
  int lane = tid & 63, wave = tid >> 6;
  int wr = wave >> 1, wc = wave & 1;
  int lrow = lane & 15, g = lane >> 4;
  int bm = blockIdx.x * TM, bn = blockIdx.y * TN;
  int z = blockIdx.z;
  const unsigned short* Ab = A + (size_t)z * sAz;
  const unsigned short* Bb = BT + (size_t)z * sBz;

  f32x4 acc[FM][FN] = {};

  for (int kk = 0; kk < Kdim; kk += 32) {
    #pragma unroll
    for (int i = 0; i < AI; i++) {
      int o = i * 4096 + tid * 16;
      const unsigned short* src = Ab + (size_t)(bm + (o >> 6)) * lda + kk + ((o & 63) >> 1);
      __builtin_amdgcn_global_load_lds((glb_u32*)src,
          (lds_u32*)((char*)As + i * 4096 + wave * 1024), 16, 0, 0);
    }
    #pragma unroll
    for (int i = 0; i < BI; i++) {
      int o = i * 4096 + tid * 16;
      const unsigned short* src = Bb + (size_t)(bn + (o >> 6)) * ldb + kk + ((o & 63) >> 1);
      __builtin_amdgcn_global_load_lds((glb_u32*)src,
          (lds_u32*)((char*)Bs + i * 4096 + wave * 1024), 16, 0, 0);
    }
    __syncthreads();
    bf16x8 af[FM], bfr[FN];
    #pragma unroll
    for (int m = 0; m < FM; m++)
      af[m] = *(const bf16x8*)((const char*)As + (wr * WM + m * 16 + lrow) * 64 + g * 16);
    #pragma unroll
    for (int n = 0; n < FN; n++)
      bfr[n] = *(const bf16x8*)((const char*)Bs + (wc * WN + n * 16 + lrow) * 64 + g * 16);
    #pragma unroll
    for (int m = 0; m < FM; m++)
      #pragma unroll
      for (int n = 0; n < FN; n++)
        acc[m][n] = __builtin_amdgcn_mfma_f32_16x16x32_bf16(af[m], bfr[n], acc[m][n], 0, 0, 0);
    __syncthreads();
  }

  int hg = hbase + z;
  float lsum[FM][4];
  #pragma unroll
  for (int m = 0; m < FM; m++) { lsum[m][0] = lsum[m][1] = lsum[m][2] = lsum[m][3] = 0.f; }

  #pragma unroll
  for (int m = 0; m < FM; m++) {
    int rb2 = bm + wr * WM + m * 16 + g * 4;       // D rows: rb2..rb2+3 (verified C/D map)
    #pragma unroll
    for (int n = 0; n < FN; n++) {
      int c = bn + wc * WN + n * 16 + lrow;        // D col
      f32x4 v = acc[m][n];
      if constexpr (EPI == 0) {
        unsigned short* C = (unsigned short*)C0;
        #pragma unroll
        for (int j = 0; j < 4; j++) C[(size_t)(rb2 + j) * 2048 + c] = f2bf(v[j]);
      } else if constexpr (EPI == 1) {
        unsigned short* P   = (unsigned short*)C0 + (size_t)z * NT * NT;
        unsigned short* PTp = (unsigned short*)C1 + (size_t)z * NT * NT;
        unsigned short pb[4];
        #pragma unroll
        for (int j = 0; j < 4; j++) {
          float p = __expf(BETA * v[j]);
          pb[j] = f2bf(p);
          lsum[m][j] += p;
          P[(size_t)(rb2 + j) * NT + c] = pb[j];
        }
        ushort4 t4; t4.x = pb[0]; t4.y = pb[1]; t4.z = pb[2]; t4.w = pb[3];
        *(ushort4*)(PTp + (size_t)c * NT + rb2) = t4;
      } else if constexpr (EPI == 2) {
        unsigned short* C = (unsigned short*)C0;
        #pragma unroll
        for (int j = 0; j < 4; j++) {
          float rl = 1.0f / L[(size_t)hg * NT + rb2 + j];
          C[(size_t)(rb2 + j) * 2048 + hg * KDZ + c] = f2bf(v[j] * rl);
        }
      } else if constexpr (EPI == 3) {
        unsigned short* C = (unsigned short*)C0;
        #pragma unroll
        for (int j = 0; j < 4; j++)
          C[(size_t)(rb2 + j) * 2048 + 1024 + hg * KDZ + c] = f2bf(v[j]);
      } else {
        float* C = (float*)C0;
        #pragma unroll
        for (int j = 0; j < 4; j++)
          C[(size_t)(rb2 + j) * 1024 + c] = -v[j];
      }
    }
  }
  if constexpr (EPI == 1) {
    #pragma unroll
    for (int m = 0; m < FM; m++) {
      int rb2 = bm + wr * WM + m * 16 + g * 4;
      #pragma unroll
      for (int j = 0; j < 4; j++) {
        float sv = lsum[m][j];
        sv += __shfl_xor(sv, 1); sv += __shfl_xor(sv, 2);
        sv += __shfl_xor(sv, 4); sv += __shfl_xor(sv, 8);
        if (lrow == 0) atomicAdd(&L[(size_t)hg * NT + rb2 + j], sv);
      }
    }
  }
}

// ------------------------------------------------------------------
extern "C" void kernel_launch(void* const* d_in, const int* in_sizes, int n_in,
                              void* d_out, int out_size, void* d_ws, size_t ws_size,
                              hipStream_t stream)
{
  (void)in_sizes; (void)n_in; (void)out_size;
  const float* g  = (const float*)d_in[0];
  const float* Wk = (const float*)d_in[1];
  const float* Wq = (const float*)d_in[2];

  char* ws = (char*)d_ws;
  size_t off = 0;
  auto alloc = [&](size_t b) -> char* {
    char* p = ws + off; off += (b + 255) & ~((size_t)255); return p;
  };
  unsigned short* gbf  = (unsigned short*)alloc((size_t)NT * TD * 2);     // 4 MB
  unsigned short* wkq  = (unsigned short*)alloc((size_t)2 * TD * TD * 2); // 4 MB
  unsigned short* twqk = (unsigned short*)alloc((size_t)TD * 2048 * 2);   // 4 MB
  unsigned short* CKQ  = (unsigned short*)alloc((size_t)NT * 2048 * 2);   // 8 MB
  unsigned short* TKQ  = (unsigned short*)alloc((size_t)NT * 2048 * 2);   // 8 MB
  unsigned short* CB12 = (unsigned short*)alloc((size_t)NT * 2048 * 2);   // 8 MB
  unsigned short* QsT  = (unsigned short*)alloc((size_t)TD * NT * 2);     // 4 MB
  float*          Lbuf = (float*)alloc((size_t)NH * NT * 4);              // 128 KB

  int CH = 16;                                    // heads per chunk (P/PT reuse)
  while (CH > 1 && off + (size_t)CH * 2 * ((size_t)NT * NT * 2) > ws_size) CH >>= 1;
  unsigned short* P  = (unsigned short*)alloc((size_t)CH * NT * NT * 2);
  unsigned short* PT = (unsigned short*)alloc((size_t)CH * NT * NT * 2);

  hipMemsetAsync(Lbuf, 0, (size_t)NH * NT * 4, stream);
  prep_kernel<<<dim3(4096), dim3(256), 0, stream>>>(g, Wk, Wq, gbf, wkq, twqk);

  // K,Q = g * [Wk;Wq]^T  -> CKQ [2048 tok][2048 = K(0:1024)|Q(1024:2048)]
  btg_kernel<128, 128, 0><<<dim3(16, 16, 1), dim3(256), 0, stream>>>(
      gbf, TD, 0LL, wkq, TD, 0LL, TD, (void*)CKQ, nullptr, nullptr, 0);
  transp_kernel<<<dim3(4096), dim3(256), 0, stream>>>(CKQ, TKQ);

  for (int hb = 0; hb < NH; hb += CH) {
    // scores: S = Q_h * K_h^T; P = exp(beta*S) (unnormalized), PT, L row-sums
    btg_kernel<128, 128, 1><<<dim3(16, 16, CH), dim3(256), 0, stream>>>(
        CKQ + TD + hb * KDZ, 2048, (long long)KDZ,
        CKQ + hb * KDZ,      2048, (long long)KDZ, KDZ,
        (void*)P, (void*)PT, Lbuf, hb);
    // B1 = (P/L) * K  -> CB12 cols [hg*64, hg*64+64)
    btg_kernel<128, 64, 2><<<dim3(16, 1, CH), dim3(256), 0, stream>>>(
        P, NT, (long long)NT * NT,
        TKQ + (size_t)hb * KDZ * 2048, 2048, (long long)KDZ * 2048, NT,
        (void*)CB12, nullptr, Lbuf, hb);
    // QsT rows for this chunk
    qst_kernel<<<dim3(CH * KDZ), dim3(256), 0, stream>>>(TKQ, Lbuf, QsT, hb * KDZ);
    // B2 = PT * (Q/L)  -> CB12 cols [1024+hg*64, ...)
    btg_kernel<128, 64, 3><<<dim3(16, 1, CH), dim3(256), 0, stream>>>(
        PT, NT, (long long)NT * NT,
        QsT + (size_t)hb * KDZ * 2048, 2048, (long long)KDZ * 2048, NT,
        (void*)CB12, nullptr, Lbuf, hb);
  }

  // out = -( B1*Wq + B2*Wk ) = - CB12 * twqk^T   (f32)
  btg_kernel<128, 128, 4><<<dim3(16, 8, 1), dim3(256), 0, stream>>>(
      CB12, 2048, 0LL, twqk, 2048, 0LL, 2048, d_out, nullptr, nullptr, 0);
}

// Round 2
// 134.978 us; speedup vs baseline: 2.3596x; 2.3596x over previous
//
#include <hip/hip_runtime.h>
#include <stdint.h>

#define NT 2048     // tokens
#define TD 1024     // token dim
#define NH 16       // heads
static constexpr float BETA = 0.125f;   // 1/sqrt(64)

typedef __attribute__((ext_vector_type(8))) short bf16x8;
typedef __attribute__((ext_vector_type(4))) float f32x4;
typedef __attribute__((address_space(3))) uint32_t lds_u32;
typedef __attribute__((address_space(1))) uint32_t glb_u32;

__device__ __forceinline__ float bf2f(unsigned short u){
  union { uint32_t u32; float f; } v; v.u32 = ((uint32_t)u) << 16; return v.f;
}
__device__ __forceinline__ unsigned short f2bf(float f){
  union { float f; uint32_t u; } v; v.f = f;
  uint32_t r = v.u + 0x7fffu + ((v.u >> 16) & 1u);   // RNE
  return (unsigned short)(r >> 16);
}
// swizzled LDS fragment read: tiles are [rows][64 bf16 = 128 B], slot = 16B unit,
// physical slot = logical ^ (row&7). Returns 8 bf16 for contraction chunk k2*32+g*8..+7.
__device__ __forceinline__ bf16x8 ldswz(const unsigned short* base, int row, int k2, int g){
  return *(const bf16x8*)((const char*)base + row*128 + ((((k2<<2)+g)^(row&7))<<4));
}

// ------------------------------------------------------------------
// prep: gbf = bf16(g); wkq = bf16([Wk;Wq]) rows hz2 x 1024;
//       twqk[d][j] = j<1024 ? Wq[j][d] : Wk[j-1024][d]  (bf16, 1024x2048)
// ------------------------------------------------------------------
__global__ __launch_bounds__(256) void prep_kernel(
    const float* __restrict__ g, const float* __restrict__ Wk, const float* __restrict__ Wq,
    unsigned short* __restrict__ gbf, unsigned short* __restrict__ wkq,
    unsigned short* __restrict__ twqk)
{
  int b = blockIdx.x;
  if (b < 1024) {
    int base = b * 2048 + threadIdx.x;
    #pragma unroll
    for (int i = 0; i < 8; i++) { int idx = base + i * 256; gbf[idx] = f2bf(g[idx]); }
  } else if (b < 2048) {
    int base = (b - 1024) * 2048 + threadIdx.x;
    #pragma unroll
    for (int i = 0; i < 8; i++) {
      int idx = base + i * 256;
      float v = (idx < (1 << 20)) ? Wk[idx] : Wq[idx - (1 << 20)];
      wkq[idx] = f2bf(v);
    }
  } else {
    int t = b - 2048;                  // 32 d-tiles x 64 j-tiles
    int dt = t & 31, jt = t >> 5;
    __shared__ float tile[32][33];
    int tx = threadIdx.x & 31, ty = threadIdx.x >> 5;
    int j0 = jt * 32, d0 = dt * 32;
    const float* src = (j0 < 1024) ? Wq : Wk;
    int jb = (j0 < 1024) ? j0 : (j0 - 1024);
    #pragma unroll
    for (int rr = 0; rr < 4; rr++)
      tile[ty + rr * 8][tx] = src[(size_t)(jb + ty + rr * 8) * 1024 + d0 + tx];
    __syncthreads();
    #pragma unroll
    for (int rr = 0; rr < 4; rr++)
      twqk[(size_t)(d0 + ty + rr * 8) * 2048 + j0 + tx] = f2bf(tile[tx][ty + rr * 8]);
  }
}

// ------------------------------------------------------------------
// qst: QsT[r][q] = TKQ[1024+r][q] / L[r>>6][q]
// ------------------------------------------------------------------
__global__ __launch_bounds__(256) void qst_kernel(const unsigned short* __restrict__ tkq,
                                                  const float* __restrict__ L,
                                                  unsigned short* __restrict__ qst)
{
  int r = blockIdx.x;
  int h = r >> 6;
  const unsigned short* src = tkq + (size_t)(1024 + r) * 2048;
  unsigned short* dst = qst + (size_t)r * 2048;
  const float* Lh = L + (size_t)h * NT;
  for (int q = threadIdx.x; q < NT; q += 256)
    dst[q] = f2bf(bf2f(src[q]) / Lh[q]);
}

// ------------------------------------------------------------------
// btg2: C = A[M x K] * BT[N x K]^T, bf16, BK=64 double-buffered 2-phase,
// swizzled LDS (row&7 XOR on 16B slots, matched pre-swizzled global source).
// EPI 0: C0 = bf16 C (ld 2048) AND C1 = transposed bf16 (ld 2048)   [KQ]
// EPI 4: C0 f32 [r][1024] = -acc                                     [out]
// ------------------------------------------------------------------
template<int TM, int TN, int EPI>
__global__ __launch_bounds__(256, 2) void btg2_kernel(
    const unsigned short* __restrict__ A, int lda,
    const unsigned short* __restrict__ BT, int ldb,
    int Kdim, void* C0, void* C1)
{
  constexpr int WM = TM / 2, WN = TN / 2, FM = WM / 16, FN = WN / 16;
  constexpr int AC = TM * 8 / 256, BC = TN * 8 / 256;
  __shared__ __align__(16) unsigned short As[2][TM * 64];
  __shared__ __align__(16) unsigned short Bs[2][TN * 64];
  int tid = threadIdx.x, lane = tid & 63, wave = tid >> 6;
  int wr = wave >> 1, wc = wave & 1, lrow = lane & 15, g = lane >> 4;
  int bm = blockIdx.x * TM, bn = blockIdx.y * TN;

  auto stage = [&](int buf, int kk) {
    #pragma unroll
    for (int i = 0; i < AC; i++) {
      int c = i * 256 + tid, row = c >> 3, sl = ((c & 7) ^ (row & 7)) << 3;
      __builtin_amdgcn_global_load_lds((glb_u32*)(A + (size_t)(bm + row) * lda + kk + sl),
          (lds_u32*)((char*)As[buf] + i * 4096 + wave * 1024), 16, 0, 0);
    }
    #pragma unroll
    for (int i = 0; i < BC; i++) {
      int c = i * 256 + tid, row = c >> 3, sl = ((c & 7) ^ (row & 7)) << 3;
      __builtin_amdgcn_global_load_lds((glb_u32*)(BT + (size_t)(bn + row) * ldb + kk + sl),
          (lds_u32*)((char*)Bs[buf] + i * 4096 + wave * 1024), 16, 0, 0);
    }
  };

  f32x4 acc[FM][FN] = {};
  stage(0, 0);
  asm volatile("s_waitcnt vmcnt(0)" ::: "memory");
  __builtin_amdgcn_sched_barrier(0);
  __builtin_amdgcn_s_barrier();
  int cur = 0;
  int nt = Kdim >> 6;
  for (int t = 0; t < nt; t++) {
    if (t + 1 < nt) stage(cur ^ 1, (t + 1) * 64);
    #pragma unroll
    for (int k2 = 0; k2 < 2; k2++) {
      bf16x8 a_[FM], b_[FN];
      #pragma unroll
      for (int m = 0; m < FM; m++) a_[m] = ldswz(As[cur], wr * WM + m * 16 + lrow, k2, g);
      #pragma unroll
      for (int n = 0; n < FN; n++) b_[n] = ldswz(Bs[cur], wc * WN + n * 16 + lrow, k2, g);
      #pragma unroll
      for (int m = 0; m < FM; m++)
        #pragma unroll
        for (int n = 0; n < FN; n++)
          acc[m][n] = __builtin_amdgcn_mfma_f32_16x16x32_bf16(a_[m], b_[n], acc[m][n], 0, 0, 0);
    }
    asm volatile("s_waitcnt vmcnt(0) lgkmcnt(0)" ::: "memory");
    __builtin_amdgcn_sched_barrier(0);
    __builtin_amdgcn_s_barrier();
    cur ^= 1;
  }
  #pragma unroll
  for (int m = 0; m < FM; m++) {
    int rb = bm + wr * WM + m * 16 + 4 * g;
    #pragma unroll
    for (int n = 0; n < FN; n++) {
      int cc = bn + wc * WN + n * 16 + lrow;
      f32x4 v = acc[m][n];
      if constexpr (EPI == 0) {
        unsigned short* C = (unsigned short*)C0;
        unsigned short* T = (unsigned short*)C1;
        unsigned short pb[4];
        #pragma unroll
        for (int j = 0; j < 4; j++) { pb[j] = f2bf(v[j]); C[(size_t)(rb + j) * 2048 + cc] = pb[j]; }
        ushort4 t4; t4.x = pb[0]; t4.y = pb[1]; t4.z = pb[2]; t4.w = pb[3];
        *(ushort4*)(T + (size_t)cc * 2048 + rb) = t4;
      } else {
        float* C = (float*)C0;
        #pragma unroll
        for (int j = 0; j < 4; j++) C[(size_t)(rb + j) * 1024 + cc] = -v[j];
      }
    }
  }
}

// ------------------------------------------------------------------
// fused flash kernel (F1: DIV=true computes B1 + L; F2: DIV=false computes B2).
// Per block: persistent 64-token block (Q for F1, K for F2) in LDS; loop over
// inner 2048 tokens in 64-tiles: S-GEMM (contract z) -> exp -> Plds[persist][inner]
// -> PV-GEMM (contract inner) with Aux = K^T (F1) or Qn^T (F2).
// ------------------------------------------------------------------
template<bool DIV>
__global__ __launch_bounds__(256, 2) void fused_kernel(
    const unsigned short* __restrict__ CKQ,   // [2048][2048]: K cols 0:1024, Q cols 1024:2048
    const unsigned short* __restrict__ AUXT,  // TKQ (F1) or QsT (F2): rows h*64+z, ld 2048
    unsigned short* __restrict__ C,           // CB12 [2048][2048]
    float* __restrict__ Lg)                   // [16][2048] (F1 only)
{
  __shared__ __align__(16) unsigned short Pblk[64 * 64];
  __shared__ __align__(16) unsigned short Ain[2][64 * 64];
  __shared__ __align__(16) unsigned short Auxs[2][64 * 64];
  __shared__ __align__(16) unsigned short Plds[64 * 64];
  __shared__ float L_lds[64];
  int tid = threadIdx.x, lane = tid & 63, wave = tid >> 6;
  int wr = wave >> 1, wc = wave & 1, lrow = lane & 15, g = lane >> 4;
  int p0 = blockIdx.x * 64, h = blockIdx.y, h64 = h * 64;
  int cA = DIV ? h64 : TD + h64;            // inner-tile cols (F1: K, F2: Q)
  int cB = DIV ? TD + h64 : h64;            // persistent cols (F1: Q, F2: K)
  const unsigned short* AuxB = AUXT + (size_t)h64 * 2048;

  #pragma unroll
  for (int i = 0; i < 2; i++) {             // persistent block
    int c = i * 256 + tid, row = c >> 3, sl = ((c & 7) ^ (row & 7)) << 3;
    __builtin_amdgcn_global_load_lds((glb_u32*)(CKQ + (size_t)(p0 + row) * 2048 + cB + sl),
        (lds_u32*)((char*)Pblk + i * 4096 + wave * 1024), 16, 0, 0);
  }
  auto stage = [&](int buf, int i0) {
    #pragma unroll
    for (int i = 0; i < 2; i++) {
      int c = i * 256 + tid, row = c >> 3, sl = ((c & 7) ^ (row & 7)) << 3;
      __builtin_amdgcn_global_load_lds((glb_u32*)(CKQ + (size_t)(i0 + row) * 2048 + cA + sl),
          (lds_u32*)((char*)Ain[buf] + i * 4096 + wave * 1024), 16, 0, 0);
    }
    #pragma unroll
    for (int i = 0; i < 2; i++) {
      int c = i * 256 + tid, row = c >> 3, sl = ((c & 7) ^ (row & 7)) << 3;
      __builtin_amdgcn_global_load_lds((glb_u32*)(AuxB + (size_t)row * 2048 + i0 + sl),
          (lds_u32*)((char*)Auxs[buf] + i * 4096 + wave * 1024), 16, 0, 0);
    }
  };
  stage(0, 0);
  if (tid < 64) L_lds[tid] = 0.f;
  asm volatile("s_waitcnt vmcnt(0)" ::: "memory");
  __builtin_amdgcn_sched_barrier(0);
  __builtin_amdgcn_s_barrier();

  f32x4 acc_pv[2][2] = {};
  float lsum0 = 0.f, lsum1 = 0.f;
  int cur = 0;
  for (int t = 0; t < 32; t++) {
    if (t < 31) stage(cur ^ 1, (t + 1) * 64);
    // ---- S-GEMM: acc_s[m][n] : row = inner (wr*32+m*16+4g+j), col = persist (wc*32+n*16+lrow)
    f32x4 acc_s[2][2] = {};
    #pragma unroll
    for (int k2 = 0; k2 < 2; k2++) {
      bf16x8 a_[2], b_[2];
      #pragma unroll
      for (int m = 0; m < 2; m++) a_[m] = ldswz(Ain[cur], wr * 32 + m * 16 + lrow, k2, g);
      #pragma unroll
      for (int n = 0; n < 2; n++) b_[n] = ldswz(Pblk, wc * 32 + n * 16 + lrow, k2, g);
      #pragma unroll
      for (int m = 0; m < 2; m++)
        #pragma unroll
        for (int n = 0; n < 2; n++)
          acc_s[m][n] = __builtin_amdgcn_mfma_f32_16x16x32_bf16(a_[m], b_[n], acc_s[m][n], 0, 0, 0);
    }
    // ---- exp + pack + write Plds[persist][inner] (b64, swizzled), accumulate L
    #pragma unroll
    for (int m = 0; m < 2; m++) {
      int i0l = wr * 32 + m * 16 + 4 * g;       // inner row base (4 consecutive)
      int slb = i0l >> 3;                        // logical 16B slot
      #pragma unroll
      for (int n = 0; n < 2; n++) {
        int p = wc * 32 + n * 16 + lrow;         // persist index
        float e0 = __expf(acc_s[m][n][0] * BETA);
        float e1 = __expf(acc_s[m][n][1] * BETA);
        float e2 = __expf(acc_s[m][n][2] * BETA);
        float e3 = __expf(acc_s[m][n][3] * BETA);
        if (DIV) { if (n == 0) lsum0 += e0 + e1 + e2 + e3; else lsum1 += e0 + e1 + e2 + e3; }
        uint2 wv;
        wv.x = ((uint32_t)f2bf(e1) << 16) | f2bf(e0);
        wv.y = ((uint32_t)f2bf(e3) << 16) | f2bf(e2);
        *(uint2*)((char*)Plds + p * 128 + ((slb ^ (p & 7)) << 4) + (g & 1) * 8) = wv;
      }
    }
    asm volatile("s_waitcnt lgkmcnt(0)" ::: "memory");
    __builtin_amdgcn_sched_barrier(0);
    __builtin_amdgcn_s_barrier();
    // ---- PV-GEMM: acc_pv[m][n] : row = persist, col = z
    #pragma unroll
    for (int k2 = 0; k2 < 2; k2++) {
      bf16x8 pa[2], pb[2];
      #pragma unroll
      for (int m = 0; m < 2; m++) pa[m] = ldswz(Plds, wr * 32 + m * 16 + lrow, k2, g);
      #pragma unroll
      for (int n = 0; n < 2; n++) pb[n] = ldswz(Auxs[cur], wc * 32 + n * 16 + lrow, k2, g);
      #pragma unroll
      for (int m = 0; m < 2; m++)
        #pragma unroll
        for (int n = 0; n < 2; n++)
          acc_pv[m][n] = __builtin_amdgcn_mfma_f32_16x16x32_bf16(pa[m], pb[n], acc_pv[m][n], 0, 0, 0);
    }
    asm volatile("s_waitcnt vmcnt(0) lgkmcnt(0)" ::: "memory");
    __builtin_amdgcn_sched_barrier(0);
    __builtin_amdgcn_s_barrier();
    cur ^= 1;
  }
  if (DIV) {
    lsum0 += __shfl_xor(lsum0, 16); lsum0 += __shfl_xor(lsum0, 32);
    lsum1 += __shfl_xor(lsum1, 16); lsum1 += __shfl_xor(lsum1, 32);
    if (g == 0) {
      atomicAdd(&L_lds[wc * 32 + lrow], lsum0);
      atomicAdd(&L_lds[wc * 32 + 16 + lrow], lsum1);
    }
  }
  __syncthreads();
  if (DIV && tid < 64) Lg[(size_t)h * NT + p0 + tid] = L_lds[tid];
  int cbase = DIV ? h64 : TD + h64;
  #pragma unroll
  for (int m = 0; m < 2; m++) {
    int pr = wr * 32 + m * 16 + 4 * g;
    #pragma unroll
    for (int n = 0; n < 2; n++) {
      int z = wc * 32 + n * 16 + lrow;
      f32x4 v = acc_pv[m][n];
      #pragma unroll
      for (int j = 0; j < 4; j++) {
        float x = v[j];
        if (DIV) x /= L_lds[pr + j];
        C[(size_t)(p0 + pr + j) * 2048 + cbase + z] = f2bf(x);
      }
    }
  }
}

// ------------------------------------------------------------------
extern "C" void kernel_launch(void* const* d_in, const int* in_sizes, int n_in,
                              void* d_out, int out_size, void* d_ws, size_t ws_size,
                              hipStream_t stream)
{
  (void)in_sizes; (void)n_in; (void)out_size; (void)ws_size;
  const float* g  = (const float*)d_in[0];
  const float* Wk = (const float*)d_in[1];
  const float* Wq = (const float*)d_in[2];

  char* ws = (char*)d_ws;
  size_t off = 0;
  auto alloc = [&](size_t b) -> char* {
    char* p = ws + off; off += (b + 255) & ~((size_t)255); return p;
  };
  unsigned short* gbf  = (unsigned short*)alloc((size_t)NT * TD * 2);     // 4 MB
  unsigned short* wkq  = (unsigned short*)alloc((size_t)2 * TD * TD * 2); // 4 MB
  unsigned short* twqk = (unsigned short*)alloc((size_t)TD * 2048 * 2);   // 4 MB
  unsigned short* CKQ  = (unsigned short*)alloc((size_t)NT * 2048 * 2);   // 8 MB
  unsigned short* TKQ  = (unsigned short*)alloc((size_t)NT * 2048 * 2);   // 8 MB
  unsigned short* CB12 = (unsigned short*)alloc((size_t)NT * 2048 * 2);   // 8 MB
  unsigned short* QsT  = (unsigned short*)alloc((size_t)TD * NT * 2);     // 4 MB
  float*          Lbuf = (float*)alloc((size_t)NH * NT * 4);              // 128 KB

  prep_kernel<<<dim3(4096), dim3(256), 0, stream>>>(g, Wk, Wq, gbf, wkq, twqk);

  // K,Q = g * [Wk;Wq]^T  -> CKQ [tok][2048] and TKQ = CKQ^T (fused transposed write)
  btg2_kernel<128, 64, 0><<<dim3(16, 32), dim3(256), 0, stream>>>(
      gbf, TD, wkq, TD, TD, (void*)CKQ, (void*)TKQ);

  // F1: B1 (normalized) -> CB12 cols [h*64, h*64+64), plus L
  fused_kernel<true><<<dim3(32, NH), dim3(256), 0, stream>>>(CKQ, TKQ, CB12, Lbuf);

  // Qn^T = Q^T / L
  qst_kernel<<<dim3(1024), dim3(256), 0, stream>>>(TKQ, Lbuf, QsT);

  // F2: B2 -> CB12 cols [1024+h*64, ...)
  fused_kernel<false><<<dim3(32, NH), dim3(256), 0, stream>>>(CKQ, QsT, CB12, nullptr);

  // out = -( CB12 * twqk^T )   (f32)
  btg2_kernel<64, 64, 4><<<dim3(32, 16), dim3(256), 0, stream>>>(
      CB12, 2048, twqk, 2048, 2048, d_out, nullptr);
}